// Round 2
// baseline (11034.079 us; speedup 1.0000x reference)
//
#include <hip/hip_runtime.h>
#include <hip/hip_bf16.h>

typedef __attribute__((ext_vector_type(8))) _Float16 f16x8;
typedef __attribute__((ext_vector_type(4))) float floatx4;

#define T_SEQ 512
#define B_SZ  64
#define I_SZ  512
#define H_SZ  1024
#define NC    3072          // x-projection cols: [r(1024) | z(1024) | h(1024)]
#define NWG   64            // persistent workgroups
#define JS    16            // H columns per WG

// ---------------- workspace layout (bytes) ----------------
// xproj fp16 [B*T][3072] : 201,326,592
// h16  fp16  [B][H]      : 131,072   (cross-WG, accessed via agent-scope ops)
// rh16 fp16  [B][H]      : 131,072   (cross-WG, accessed via agent-scope ops)
// flags u32  [NWG]       : 256
static const size_t XPROJ_BYTES = (size_t)B_SZ * T_SEQ * NC * 2;
static const size_t H16_OFF = XPROJ_BYTES;
static const size_t RH_OFF  = H16_OFF + (size_t)B_SZ * H_SZ * 2;
static const size_t FLG_OFF = RH_OFF + (size_t)B_SZ * H_SZ * 2;

__device__ __forceinline__ f16x8 cvt8(float4 a, float4 b) {
  f16x8 v;
  v[0] = (_Float16)a.x; v[1] = (_Float16)a.y; v[2] = (_Float16)a.z; v[3] = (_Float16)a.w;
  v[4] = (_Float16)b.x; v[5] = (_Float16)b.y; v[6] = (_Float16)b.z; v[7] = (_Float16)b.w;
  return v;
}

// ---------------- init: h16 + flags ----------------
__global__ void init_h_kernel(const float* __restrict__ h0,
                              _Float16* __restrict__ h16,
                              unsigned* __restrict__ flags) {
  int i = blockIdx.x * blockDim.x + threadIdx.x;
  if (i < B_SZ * H_SZ) h16[i] = (_Float16)h0[i];
  if (blockIdx.x == 0 && threadIdx.x < NWG) flags[threadIdx.x] = 0u;
}

// ---------------- pre-GEMM: xproj = x @ Wx^T + bias (fp16 out) ----------------
__global__ __launch_bounds__(256) void pregemm_kernel(
    const float* __restrict__ X, const float* __restrict__ Wrz,
    const float* __restrict__ Wh, const float* __restrict__ brz,
    const float* __restrict__ bh, _Float16* __restrict__ xproj) {
  __shared__ __align__(16) char smem[128 * 64 * 2];   // As | Bs, 32 halves (64B) per row
  char* Asb = smem;
  char* Bsb = smem + 128 * 64;
  const int tid = threadIdx.x;
  const int w = tid >> 6, l = tid & 63;
  const int lg = l >> 4, ln = l & 15;
  const int wm = w >> 1, wn = w & 1;
  const int m0 = blockIdx.x * 128;
  const int n0 = blockIdx.y * 128;
  const int rs = tid >> 1;          // staging row 0..127
  const int ks = (tid & 1) * 16;    // staging k-seg (floats)

  floatx4 acc[4][4];
#pragma unroll
  for (int i = 0; i < 4; i++)
#pragma unroll
    for (int j = 0; j < 4; j++) acc[i][j] = (floatx4){0.f, 0.f, 0.f, 0.f};

  const float* garow = X + (size_t)(m0 + rs) * I_SZ + ks;
  const int nrow = n0 + rs;
  const float* gbrow = (nrow < 2048) ? (Wrz + (size_t)nrow * 1536 + ks)
                                     : (Wh + (size_t)(nrow - 2048) * 1536 + ks);
  for (int kt = 0; kt < I_SZ; kt += 32) {
    float4 a0 = ((const float4*)(garow + kt))[0];
    float4 a1 = ((const float4*)(garow + kt))[1];
    float4 a2 = ((const float4*)(garow + kt))[2];
    float4 a3 = ((const float4*)(garow + kt))[3];
    float4 b0 = ((const float4*)(gbrow + kt))[0];
    float4 b1 = ((const float4*)(gbrow + kt))[1];
    float4 b2 = ((const float4*)(gbrow + kt))[2];
    float4 b3 = ((const float4*)(gbrow + kt))[3];
    __syncthreads();
    {
      int c0 = ks >> 3;
      f16x8* wp = (f16x8*)(Asb + rs * 64);
      wp[(c0)     ^ (rs & 3)] = cvt8(a0, a1);
      wp[(c0 + 1) ^ (rs & 3)] = cvt8(a2, a3);
      f16x8* wq = (f16x8*)(Bsb + rs * 64);
      wq[(c0)     ^ (rs & 3)] = cvt8(b0, b1);
      wq[(c0 + 1) ^ (rs & 3)] = cvt8(b2, b3);
    }
    __syncthreads();
    f16x8 af[4], bf[4];
#pragma unroll
    for (int i = 0; i < 4; i++) {
      int ra = wm * 64 + i * 16 + ln;
      af[i] = ((const f16x8*)(Asb + ra * 64))[lg ^ (ra & 3)];
      int rb = wn * 64 + i * 16 + ln;
      bf[i] = ((const f16x8*)(Bsb + rb * 64))[lg ^ (rb & 3)];
    }
#pragma unroll
    for (int i = 0; i < 4; i++)
#pragma unroll
      for (int j = 0; j < 4; j++)
        acc[i][j] = __builtin_amdgcn_mfma_f32_16x16x32_f16(af[i], bf[j], acc[i][j], 0, 0, 0);
  }
#pragma unroll
  for (int j = 0; j < 4; j++) {
    int n = n0 + wn * 64 + j * 16 + ln;
    float bias = (n < 2048) ? (brz[n] + ((n >= 1024) ? 1.0f : 0.0f)) : bh[n - 2048];
#pragma unroll
    for (int i = 0; i < 4; i++) {
      int mrow = m0 + wm * 64 + i * 16 + 4 * lg;
#pragma unroll
      for (int q = 0; q < 4; q++) {
        xproj[(size_t)(mrow + q) * NC + n] = (_Float16)(acc[i][j][q] + bias);
      }
    }
  }
}

// ---------------- agent-scope (LIC-coherent) load of a 16B fp16 fragment ----------------
__device__ __forceinline__ f16x8 ald16(const _Float16* p) {
  union { unsigned long long u[2]; f16x8 v; } x;
  unsigned long long* q = (unsigned long long*)p;
  x.u[0] = __hip_atomic_load(q,     __ATOMIC_RELAXED, __HIP_MEMORY_SCOPE_AGENT);
  x.u[1] = __hip_atomic_load(q + 1, __ATOMIC_RELAXED, __HIP_MEMORY_SCOPE_AGENT);
  return x.v;
}

// Pack (even,odd) column pair across lane pair via shfl, store one u32 write-through.
// All 64 lanes must execute (shfl); exactly one lane of each pair stores per q.
__device__ __forceinline__ void pack_store_pair(unsigned* dst, int ln, int q,
                                                float v, int b, int cw) {
  _Float16 hh = (_Float16)v;
  unsigned short ms = __builtin_bit_cast(unsigned short, hh);
  unsigned ov = ((unsigned)__shfl_xor((int)ms, 1, 64)) & 0xffffu;
  unsigned word = (ln & 1) ? (ov | ((unsigned)ms << 16)) : (((unsigned)ms) | (ov << 16));
  bool st = (q & 2) ? (bool)(ln & 1) : !(ln & 1);
  if (st)
    __hip_atomic_store(dst + (size_t)b * (H_SZ / 2) + cw, word,
                       __ATOMIC_RELAXED, __HIP_MEMORY_SCOPE_AGENT);
}

// ---------------- fence-free grid barrier ----------------
// Own write-through stores are drained by the vmcnt(0) the compiler emits for
// __syncthreads; flag store + poll are agent-scope relaxed (no L2 flush ever).
__device__ __forceinline__ void wg_barrier(unsigned* flags, unsigned target) {
  __syncthreads();
  if (threadIdx.x == 0)
    __hip_atomic_store(&flags[blockIdx.x], target, __ATOMIC_RELAXED,
                       __HIP_MEMORY_SCOPE_AGENT);
  unsigned v;
  const int l = threadIdx.x & 63;
  do {
    v = __hip_atomic_load(&flags[l], __ATOMIC_RELAXED, __HIP_MEMORY_SCOPE_AGENT);
  } while (__all((int)(v >= target)) == 0);
}

// ---------------- persistent GRU recurrence ----------------
__global__ __launch_bounds__(256) void gru_persistent_kernel(
    const float* __restrict__ Wrz, const float* __restrict__ Wh,
    const float* __restrict__ h0, const _Float16* __restrict__ xproj,
    float* __restrict__ Y, unsigned* __restrict__ h16u,
    unsigned* __restrict__ rh16u, unsigned* __restrict__ flags) {
  __shared__ __align__(16) char smem[98304];  // 32*2048 (wA) + 16*2048 (wB)
  const int g = blockIdx.x;
  const int tid = threadIdx.x;
  const int w = tid >> 6, l = tid & 63;
  const int lg = l >> 4, ln = l & 15;

  // load + convert recurrent weights into LDS (XOR-swizzled 16B chunks)
  for (int it = tid; it < 48 * 128; it += 256) {
    int r = it >> 7;
    int c = it & 127;
    const float* src;
    int n; size_t base;
    if (r < 32) {
      int gr = (r < 16) ? (JS * g + r) : (1024 + JS * g + (r - 16));
      src = Wrz + (size_t)gr * 1536 + 512 + c * 8;
      n = r; base = 0;
    } else {
      int gr = JS * g + (r - 32);
      src = Wh + (size_t)gr * 1536 + 512 + c * 8;
      n = r - 32; base = 65536;
    }
    float4 f0 = ((const float4*)src)[0];
    float4 f1 = ((const float4*)src)[1];
    ((f16x8*)(smem + base + (size_t)n * 2048))[c ^ (n & 7)] = cvt8(f0, f1);
  }
  __syncthreads();

  const int jg = JS * g + ln;            // own H-column
  const int cw = 8 * g + (ln >> 1);      // u32 word index of (jg&~1) pair
  const int sw = ln & 7;
  const f16x8* bpr = (const f16x8*)(smem + (size_t)ln * 2048);
  const f16x8* bpz = (const f16x8*)(smem + (size_t)(16 + ln) * 2048);
  const f16x8* bph = (const f16x8*)(smem + 65536 + (size_t)ln * 2048);
  const _Float16* h16h  = (const _Float16*)h16u;
  const _Float16* rh16h = (const _Float16*)rh16u;

  unsigned bar = 0;
  float zq[4], hmv[4];
  // fp32 master h lives entirely in registers (owner-private columns)
#pragma unroll
  for (int q = 0; q < 4; q++) {
    int b = 16 * w + 4 * lg + q;
    hmv[q] = h0[b * H_SZ + jg];
  }

  for (int t = 0; t < T_SEQ; ++t) {
    // staged x-projections (private, normal cached loads), issued early
    float xr[4], xz[4], xh[4];
#pragma unroll
    for (int q = 0; q < 4; q++) {
      int b = 16 * w + 4 * lg + q;
      size_t row = ((size_t)b * T_SEQ + t) * NC;
      xr[q] = (float)xproj[row + jg];
      xz[q] = (float)xproj[row + 1024 + jg];
      xh[q] = (float)xproj[row + 2048 + jg];
    }
    // ---------------- phase A: r,z ----------------
    {
      floatx4 a00 = {0,0,0,0}, a01 = {0,0,0,0}, a10 = {0,0,0,0}, a11 = {0,0,0,0};
      const _Float16* ap = h16h + (16 * w + ln) * H_SZ + 8 * lg;
#pragma unroll
      for (int ki = 0; ki < 32; ++ki) {
        f16x8 a  = ald16(ap + 32 * ki);
        f16x8 br = bpr[(4 * ki + lg) ^ sw];
        f16x8 bz = bpz[(4 * ki + lg) ^ sw];
        if (ki & 1) {
          a01 = __builtin_amdgcn_mfma_f32_16x16x32_f16(a, br, a01, 0, 0, 0);
          a11 = __builtin_amdgcn_mfma_f32_16x16x32_f16(a, bz, a11, 0, 0, 0);
        } else {
          a00 = __builtin_amdgcn_mfma_f32_16x16x32_f16(a, br, a00, 0, 0, 0);
          a10 = __builtin_amdgcn_mfma_f32_16x16x32_f16(a, bz, a10, 0, 0, 0);
        }
      }
      floatx4 Dr = a00 + a01, Dz = a10 + a11;
#pragma unroll
      for (int q = 0; q < 4; q++) {
        int b = 16 * w + 4 * lg + q;
        float rr = 1.f / (1.f + __expf(-(Dr[q] + xr[q])));
        zq[q]    = 1.f / (1.f + __expf(-(Dz[q] + xz[q])));
        pack_store_pair(rh16u, ln, q, rr * hmv[q], b, cw);
      }
    }
    ++bar; wg_barrier(flags, bar);
    // ---------------- phase B: hhat, h_new ----------------
    {
      floatx4 a0 = {0,0,0,0}, a1 = {0,0,0,0};
      const _Float16* ap = rh16h + (16 * w + ln) * H_SZ + 8 * lg;
#pragma unroll
      for (int ki = 0; ki < 32; ++ki) {
        f16x8 a = ald16(ap + 32 * ki);
        f16x8 bh8 = bph[(4 * ki + lg) ^ sw];
        if (ki & 1) a1 = __builtin_amdgcn_mfma_f32_16x16x32_f16(a, bh8, a1, 0, 0, 0);
        else        a0 = __builtin_amdgcn_mfma_f32_16x16x32_f16(a, bh8, a0, 0, 0, 0);
      }
      floatx4 Dh = a0 + a1;
#pragma unroll
      for (int q = 0; q < 4; q++) {
        int b = 16 * w + 4 * lg + q;
        float hhat = tanhf(Dh[q] + xh[q]);
        float hn = zq[q] * hmv[q] + (1.f - zq[q]) * hhat;
        Y[((size_t)b * T_SEQ + t) * H_SZ + jg] = hn;
        hmv[q] = hn;
        pack_store_pair(h16u, ln, q, hn, b, cw);
      }
    }
    ++bar; wg_barrier(flags, bar);
  }
}

// ---------------- launch ----------------
extern "C" void kernel_launch(void* const* d_in, const int* in_sizes, int n_in,
                              void* d_out, int out_size, void* d_ws, size_t ws_size,
                              hipStream_t stream) {
  const float* X   = (const float*)d_in[0];
  const float* h0  = (const float*)d_in[1];
  const float* Wrz = (const float*)d_in[2];
  const float* brz = (const float*)d_in[3];
  const float* Wh  = (const float*)d_in[4];
  const float* bh  = (const float*)d_in[5];
  float* Y = (float*)d_out;
  char* ws = (char*)d_ws;

  _Float16* xproj = (_Float16*)(ws);
  _Float16* h16   = (_Float16*)(ws + H16_OFF);
  unsigned* h16u  = (unsigned*)(ws + H16_OFF);
  unsigned* rh16u = (unsigned*)(ws + RH_OFF);
  unsigned* flags = (unsigned*)(ws + FLG_OFF);

  hipLaunchKernelGGL(init_h_kernel, dim3(256), dim3(256), 0, stream, h0, h16, flags);
  hipLaunchKernelGGL(pregemm_kernel, dim3(256, 24), dim3(256), 0, stream,
                     X, Wrz, Wh, brz, bh, xproj);

  void* kargs[] = { (void*)&Wrz, (void*)&Wh, (void*)&h0, (void*)&xproj, (void*)&Y,
                    (void*)&h16u, (void*)&rh16u, (void*)&flags };
  hipLaunchCooperativeKernel((void*)gru_persistent_kernel, dim3(NWG), dim3(256),
                             kargs, 0, stream);
}

// Round 5
// 10965.363 us; speedup vs baseline: 1.0063x; 1.0063x over previous
//
#include <hip/hip_runtime.h>
#include <hip/hip_bf16.h>

typedef __attribute__((ext_vector_type(8))) _Float16 f16x8;
typedef __attribute__((ext_vector_type(4))) float floatx4;

#define T_SEQ 512
#define B_SZ  64
#define I_SZ  512
#define H_SZ  1024
#define NC    3072          // x-projection cols: [r(1024) | z(1024) | h(1024)]
#define NWG   64            // persistent workgroups
#define JS    16            // H columns per WG

// ---------------- workspace layout (bytes) ----------------
// xproj fp16 [B*T][3072] : 201,326,592
// h16  fp16  [64][1024]  : 131,072  (cross-WG, agent-scope)
// rh16 fp16  [64][1024]  : 131,072
// flags u32  [NWG]       : 256
static const size_t XPROJ_BYTES = (size_t)B_SZ * T_SEQ * NC * 2;
static const size_t H16_OFF = XPROJ_BYTES;
static const size_t RH_OFF  = H16_OFF + (size_t)B_SZ * H_SZ * 2;
static const size_t FLG_OFF = RH_OFF + (size_t)B_SZ * H_SZ * 2;

__device__ __forceinline__ f16x8 cvt8(float4 a, float4 b) {
  f16x8 v;
  v[0] = (_Float16)a.x; v[1] = (_Float16)a.y; v[2] = (_Float16)a.z; v[3] = (_Float16)a.w;
  v[4] = (_Float16)b.x; v[5] = (_Float16)b.y; v[6] = (_Float16)b.z; v[7] = (_Float16)b.w;
  return v;
}

// ---------------- init: h16 + flags ----------------
__global__ void init_h_kernel(const float* __restrict__ h0,
                              _Float16* __restrict__ h16,
                              unsigned* __restrict__ flags) {
  int i = blockIdx.x * blockDim.x + threadIdx.x;
  if (i < B_SZ * H_SZ) h16[i] = (_Float16)h0[i];
  if (blockIdx.x == 0 && threadIdx.x < NWG) flags[threadIdx.x] = 0u;
}

// ---------------- pre-GEMM: xproj = x @ Wx^T + bias (fp16 out) ----------------
__global__ __launch_bounds__(256) void pregemm_kernel(
    const float* __restrict__ X, const float* __restrict__ Wrz,
    const float* __restrict__ Wh, const float* __restrict__ brz,
    const float* __restrict__ bh, _Float16* __restrict__ xproj) {
  __shared__ __align__(16) char smem[128 * 64 * 2];   // As | Bs, 32 halves (64B) per row
  char* Asb = smem;
  char* Bsb = smem + 128 * 64;
  const int tid = threadIdx.x;
  const int w = tid >> 6, l = tid & 63;
  const int lg = l >> 4, ln = l & 15;
  const int wm = w >> 1, wn = w & 1;
  const int m0 = blockIdx.x * 128;
  const int n0 = blockIdx.y * 128;
  const int rs = tid >> 1;          // staging row 0..127
  const int ks = (tid & 1) * 16;    // staging k-seg (floats)

  floatx4 acc[4][4];
#pragma unroll
  for (int i = 0; i < 4; i++)
#pragma unroll
    for (int j = 0; j < 4; j++) acc[i][j] = (floatx4){0.f, 0.f, 0.f, 0.f};

  const float* garow = X + (size_t)(m0 + rs) * I_SZ + ks;
  const int nrow = n0 + rs;
  const float* gbrow = (nrow < 2048) ? (Wrz + (size_t)nrow * 1536 + ks)
                                     : (Wh + (size_t)(nrow - 2048) * 1536 + ks);
  for (int kt = 0; kt < I_SZ; kt += 32) {
    float4 a0 = ((const float4*)(garow + kt))[0];
    float4 a1 = ((const float4*)(garow + kt))[1];
    float4 a2 = ((const float4*)(garow + kt))[2];
    float4 a3 = ((const float4*)(garow + kt))[3];
    float4 b0 = ((const float4*)(gbrow + kt))[0];
    float4 b1 = ((const float4*)(gbrow + kt))[1];
    float4 b2 = ((const float4*)(gbrow + kt))[2];
    float4 b3 = ((const float4*)(gbrow + kt))[3];
    __syncthreads();
    {
      int c0 = ks >> 3;
      f16x8* wp = (f16x8*)(Asb + rs * 64);
      wp[(c0)     ^ (rs & 3)] = cvt8(a0, a1);
      wp[(c0 + 1) ^ (rs & 3)] = cvt8(a2, a3);
      f16x8* wq = (f16x8*)(Bsb + rs * 64);
      wq[(c0)     ^ (rs & 3)] = cvt8(b0, b1);
      wq[(c0 + 1) ^ (rs & 3)] = cvt8(b2, b3);
    }
    __syncthreads();
    f16x8 af[4], bf[4];
#pragma unroll
    for (int i = 0; i < 4; i++) {
      int ra = wm * 64 + i * 16 + ln;
      af[i] = ((const f16x8*)(Asb + ra * 64))[lg ^ (ra & 3)];
      int rb = wn * 64 + i * 16 + ln;
      bf[i] = ((const f16x8*)(Bsb + rb * 64))[lg ^ (rb & 3)];
    }
#pragma unroll
    for (int i = 0; i < 4; i++)
#pragma unroll
      for (int j = 0; j < 4; j++)
        acc[i][j] = __builtin_amdgcn_mfma_f32_16x16x32_f16(af[i], bf[j], acc[i][j], 0, 0, 0);
  }
#pragma unroll
  for (int j = 0; j < 4; j++) {
    int n = n0 + wn * 64 + j * 16 + ln;
    float bias = (n < 2048) ? (brz[n] + ((n >= 1024) ? 1.0f : 0.0f)) : bh[n - 2048];
#pragma unroll
    for (int i = 0; i < 4; i++) {
      int mrow = m0 + wm * 64 + i * 16 + 4 * lg;
#pragma unroll
      for (int q = 0; q < 4; q++) {
        xproj[(size_t)(mrow + q) * NC + n] = (_Float16)(acc[i][j][q] + bias);
      }
    }
  }
}

// ---------------- agent-scope (LIC-coherent) 16B fp16 load ----------------
__device__ __forceinline__ f16x8 ald16(const _Float16* p) {
  union { unsigned long long u[2]; f16x8 v; } x;
  unsigned long long* q = (unsigned long long*)p;
  x.u[0] = __hip_atomic_load(q,     __ATOMIC_RELAXED, __HIP_MEMORY_SCOPE_AGENT);
  x.u[1] = __hip_atomic_load(q + 1, __ATOMIC_RELAXED, __HIP_MEMORY_SCOPE_AGENT);
  return x.v;
}

// Pack (even,odd) column pair across lane pair via shfl, store one u32 write-through.
__device__ __forceinline__ void pack_store_pair(unsigned* dst, int ln, int q,
                                                float v, int b, int cw) {
  _Float16 hh = (_Float16)v;
  unsigned short ms = __builtin_bit_cast(unsigned short, hh);
  unsigned ov = ((unsigned)__shfl_xor((int)ms, 1, 64)) & 0xffffu;
  unsigned word = (ln & 1) ? (ov | ((unsigned)ms << 16)) : (((unsigned)ms) | (ov << 16));
  bool st = (q & 2) ? (bool)(ln & 1) : !(ln & 1);
  if (st)
    __hip_atomic_store(dst + (size_t)b * (H_SZ / 2) + cw, word,
                       __ATOMIC_RELAXED, __HIP_MEMORY_SCOPE_AGENT);
}

// ---------------- fence-free grid barrier (round-2 proven, verbatim) ----------------
__device__ __forceinline__ void wg_barrier(unsigned* flags, unsigned target) {
  __syncthreads();
  if (threadIdx.x == 0)
    __hip_atomic_store(&flags[blockIdx.x], target, __ATOMIC_RELAXED,
                       __HIP_MEMORY_SCOPE_AGENT);
  unsigned v;
  const int l = threadIdx.x & 63;
  do {
    v = __hip_atomic_load(&flags[l], __ATOMIC_RELAXED, __HIP_MEMORY_SCOPE_AGENT);
  } while (__all((int)(v >= target)) == 0);
}

// ---------------- persistent GRU recurrence ----------------
__global__ __launch_bounds__(256) void gru_persistent_kernel(
    const float* __restrict__ Wrz, const float* __restrict__ Wh,
    const float* __restrict__ h0, const _Float16* __restrict__ xproj,
    float* __restrict__ Y, unsigned* __restrict__ h16u,
    unsigned* __restrict__ rh16u, unsigned* __restrict__ flags) {
  __shared__ __align__(16) char smem[98304];  // 32*2048 (wA) + 16*2048 (wB)
  const int g = blockIdx.x;
  const int tid = threadIdx.x;
  const int w = tid >> 6, l = tid & 63;
  const int lg = l >> 4, ln = l & 15;

  // load + convert recurrent weights into LDS (XOR-swizzled 16B chunks)
  for (int it = tid; it < 48 * 128; it += 256) {
    int r = it >> 7;
    int c = it & 127;
    const float* src;
    int n; size_t base;
    if (r < 32) {
      int gr = (r < 16) ? (JS * g + r) : (1024 + JS * g + (r - 16));
      src = Wrz + (size_t)gr * 1536 + 512 + c * 8;
      n = r; base = 0;
    } else {
      int gr = JS * g + (r - 32);
      src = Wh + (size_t)gr * 1536 + 512 + c * 8;
      n = r - 32; base = 65536;
    }
    float4 f0 = ((const float4*)src)[0];
    float4 f1 = ((const float4*)src)[1];
    ((f16x8*)(smem + base + (size_t)n * 2048))[c ^ (n & 7)] = cvt8(f0, f1);
  }
  __syncthreads();

  const int jg = JS * g + ln;            // own H-column
  const int cw = 8 * g + (ln >> 1);      // u32 word index of (jg&~1) pair
  const int sw = ln & 7;
  const f16x8* bpr = (const f16x8*)(smem + (size_t)ln * 2048);
  const f16x8* bpz = (const f16x8*)(smem + (size_t)(16 + ln) * 2048);
  const f16x8* bph = (const f16x8*)(smem + 65536 + (size_t)ln * 2048);
  const _Float16* h16h  = (const _Float16*)h16u;
  const _Float16* rh16h = (const _Float16*)rh16u;

  unsigned bar = 0;
  float zq[4], hmv[4];
  // fp32 master h lives entirely in registers (owner-private columns)
#pragma unroll
  for (int q = 0; q < 4; q++) {
    int b = 16 * w + 4 * lg + q;
    hmv[q] = h0[b * H_SZ + jg];
  }

  const _Float16* apA = h16h  + (size_t)(16 * w + ln) * H_SZ + 8 * lg;
  const _Float16* apB = rh16h + (size_t)(16 * w + ln) * H_SZ + 8 * lg;

  for (int t = 0; t < T_SEQ; ++t) {
    // staged x-projections (private, normal cached loads), issued early
    float xr[4], xz[4], xh[4];
#pragma unroll
    for (int q = 0; q < 4; q++) {
      int b = 16 * w + 4 * lg + q;
      size_t row = ((size_t)b * T_SEQ + t) * NC;
      xr[q] = (float)xproj[row + jg];
      xz[q] = (float)xproj[row + 1024 + jg];
      xh[q] = (float)xproj[row + 2048 + jg];
    }
    // ---------------- phase A: r,z (depth-16 double-buffered operand loads) ----------------
    {
      floatx4 a00 = {0.f,0.f,0.f,0.f}, a01 = {0.f,0.f,0.f,0.f};
      floatx4 a10 = {0.f,0.f,0.f,0.f}, a11 = {0.f,0.f,0.f,0.f};
      f16x8 A0[8], A1[8];
#pragma unroll
      for (int i = 0; i < 8; ++i) A0[i] = ald16(apA + 32 * i);
#pragma unroll
      for (int i = 0; i < 8; ++i) A1[i] = ald16(apA + 32 * (8 + i));
#pragma unroll
      for (int i = 0; i < 8; ++i) {          // consume ki = 0..7
        f16x8 br = bpr[(4 * i + lg) ^ sw];
        f16x8 bz = bpz[(4 * i + lg) ^ sw];
        if (i & 1) { a01 = __builtin_amdgcn_mfma_f32_16x16x32_f16(A0[i], br, a01, 0, 0, 0);
                     a11 = __builtin_amdgcn_mfma_f32_16x16x32_f16(A0[i], bz, a11, 0, 0, 0); }
        else       { a00 = __builtin_amdgcn_mfma_f32_16x16x32_f16(A0[i], br, a00, 0, 0, 0);
                     a10 = __builtin_amdgcn_mfma_f32_16x16x32_f16(A0[i], bz, a10, 0, 0, 0); }
      }
#pragma unroll
      for (int i = 0; i < 8; ++i) A0[i] = ald16(apA + 32 * (16 + i));
#pragma unroll
      for (int i = 0; i < 8; ++i) {          // consume ki = 8..15
        int ki = 8 + i;
        f16x8 br = bpr[(4 * ki + lg) ^ sw];
        f16x8 bz = bpz[(4 * ki + lg) ^ sw];
        if (i & 1) { a01 = __builtin_amdgcn_mfma_f32_16x16x32_f16(A1[i], br, a01, 0, 0, 0);
                     a11 = __builtin_amdgcn_mfma_f32_16x16x32_f16(A1[i], bz, a11, 0, 0, 0); }
        else       { a00 = __builtin_amdgcn_mfma_f32_16x16x32_f16(A1[i], br, a00, 0, 0, 0);
                     a10 = __builtin_amdgcn_mfma_f32_16x16x32_f16(A1[i], bz, a10, 0, 0, 0); }
      }
#pragma unroll
      for (int i = 0; i < 8; ++i) A1[i] = ald16(apA + 32 * (24 + i));
#pragma unroll
      for (int i = 0; i < 8; ++i) {          // consume ki = 16..23
        int ki = 16 + i;
        f16x8 br = bpr[(4 * ki + lg) ^ sw];
        f16x8 bz = bpz[(4 * ki + lg) ^ sw];
        if (i & 1) { a01 = __builtin_amdgcn_mfma_f32_16x16x32_f16(A0[i], br, a01, 0, 0, 0);
                     a11 = __builtin_amdgcn_mfma_f32_16x16x32_f16(A0[i], bz, a11, 0, 0, 0); }
        else       { a00 = __builtin_amdgcn_mfma_f32_16x16x32_f16(A0[i], br, a00, 0, 0, 0);
                     a10 = __builtin_amdgcn_mfma_f32_16x16x32_f16(A0[i], bz, a10, 0, 0, 0); }
      }
#pragma unroll
      for (int i = 0; i < 8; ++i) {          // consume ki = 24..31
        int ki = 24 + i;
        f16x8 br = bpr[(4 * ki + lg) ^ sw];
        f16x8 bz = bpz[(4 * ki + lg) ^ sw];
        if (i & 1) { a01 = __builtin_amdgcn_mfma_f32_16x16x32_f16(A1[i], br, a01, 0, 0, 0);
                     a11 = __builtin_amdgcn_mfma_f32_16x16x32_f16(A1[i], bz, a11, 0, 0, 0); }
        else       { a00 = __builtin_amdgcn_mfma_f32_16x16x32_f16(A1[i], br, a00, 0, 0, 0);
                     a10 = __builtin_amdgcn_mfma_f32_16x16x32_f16(A1[i], bz, a10, 0, 0, 0); }
      }
      floatx4 Dr = a00 + a01, Dz = a10 + a11;
#pragma unroll
      for (int q = 0; q < 4; q++) {
        int b = 16 * w + 4 * lg + q;
        float rr = 1.f / (1.f + __expf(-(Dr[q] + xr[q])));
        zq[q]    = 1.f / (1.f + __expf(-(Dz[q] + xz[q])));
        pack_store_pair(rh16u, ln, q, rr * hmv[q], b, cw);
      }
    }
    ++bar; wg_barrier(flags, bar);
    // ---------------- phase B: hhat, h_new ----------------
    {
      floatx4 c0 = {0.f,0.f,0.f,0.f}, c1 = {0.f,0.f,0.f,0.f};
      f16x8 A0[8], A1[8];
#pragma unroll
      for (int i = 0; i < 8; ++i) A0[i] = ald16(apB + 32 * i);
#pragma unroll
      for (int i = 0; i < 8; ++i) A1[i] = ald16(apB + 32 * (8 + i));
#pragma unroll
      for (int i = 0; i < 8; ++i) {          // ki = 0..7
        f16x8 bb = bph[(4 * i + lg) ^ sw];
        if (i & 1) c1 = __builtin_amdgcn_mfma_f32_16x16x32_f16(A0[i], bb, c1, 0, 0, 0);
        else       c0 = __builtin_amdgcn_mfma_f32_16x16x32_f16(A0[i], bb, c0, 0, 0, 0);
      }
#pragma unroll
      for (int i = 0; i < 8; ++i) A0[i] = ald16(apB + 32 * (16 + i));
#pragma unroll
      for (int i = 0; i < 8; ++i) {          // ki = 8..15
        int ki = 8 + i;
        f16x8 bb = bph[(4 * ki + lg) ^ sw];
        if (i & 1) c1 = __builtin_amdgcn_mfma_f32_16x16x32_f16(A1[i], bb, c1, 0, 0, 0);
        else       c0 = __builtin_amdgcn_mfma_f32_16x16x32_f16(A1[i], bb, c0, 0, 0, 0);
      }
#pragma unroll
      for (int i = 0; i < 8; ++i) A1[i] = ald16(apB + 32 * (24 + i));
#pragma unroll
      for (int i = 0; i < 8; ++i) {          // ki = 16..23
        int ki = 16 + i;
        f16x8 bb = bph[(4 * ki + lg) ^ sw];
        if (i & 1) c1 = __builtin_amdgcn_mfma_f32_16x16x32_f16(A0[i], bb, c1, 0, 0, 0);
        else       c0 = __builtin_amdgcn_mfma_f32_16x16x32_f16(A0[i], bb, c0, 0, 0, 0);
      }
#pragma unroll
      for (int i = 0; i < 8; ++i) {          // ki = 24..31
        int ki = 24 + i;
        f16x8 bb = bph[(4 * ki + lg) ^ sw];
        if (i & 1) c1 = __builtin_amdgcn_mfma_f32_16x16x32_f16(A1[i], bb, c1, 0, 0, 0);
        else       c0 = __builtin_amdgcn_mfma_f32_16x16x32_f16(A1[i], bb, c0, 0, 0, 0);
      }
      floatx4 Dh = c0 + c1;
#pragma unroll
      for (int q = 0; q < 4; q++) {
        int b = 16 * w + 4 * lg + q;
        float hhat = tanhf(Dh[q] + xh[q]);
        float hn = zq[q] * hmv[q] + (1.f - zq[q]) * hhat;
        Y[((size_t)b * T_SEQ + t) * H_SZ + jg] = hn;
        hmv[q] = hn;
        pack_store_pair(h16u, ln, q, hn, b, cw);
      }
    }
    ++bar; wg_barrier(flags, bar);
  }
}

// ---------------- launch ----------------
extern "C" void kernel_launch(void* const* d_in, const int* in_sizes, int n_in,
                              void* d_out, int out_size, void* d_ws, size_t ws_size,
                              hipStream_t stream) {
  const float* X   = (const float*)d_in[0];
  const float* h0  = (const float*)d_in[1];
  const float* Wrz = (const float*)d_in[2];
  const float* brz = (const float*)d_in[3];
  const float* Wh  = (const float*)d_in[4];
  const float* bh  = (const float*)d_in[5];
  float* Y = (float*)d_out;
  char* ws = (char*)d_ws;

  _Float16* xproj = (_Float16*)(ws);
  _Float16* h16   = (_Float16*)(ws + H16_OFF);
  unsigned* h16u  = (unsigned*)(ws + H16_OFF);
  unsigned* rh16u = (unsigned*)(ws + RH_OFF);
  unsigned* flags = (unsigned*)(ws + FLG_OFF);

  hipLaunchKernelGGL(init_h_kernel, dim3(256), dim3(256), 0, stream, h0, h16, flags);
  hipLaunchKernelGGL(pregemm_kernel, dim3(256, 24), dim3(256), 0, stream,
                     X, Wrz, Wh, brz, bh, xproj);

  void* kargs[] = { (void*)&Wrz, (void*)&Wh, (void*)&h0, (void*)&xproj, (void*)&Y,
                    (void*)&h16u, (void*)&rh16u, (void*)&flags };
  hipError_t ce = hipLaunchCooperativeKernel((void*)gru_persistent_kernel,
                                             dim3(NWG), dim3(256), kargs, 0, stream);
  if (ce != hipSuccess) {
    // fallback: plain launch — 64 WGs x 96KB LDS are trivially co-resident on 256 CUs
    hipLaunchKernelGGL(gru_persistent_kernel, dim3(NWG), dim3(256), 0, stream,
                       Wrz, Wh, h0, xproj, Y, h16u, rh16u, flags);
  }
}

// Round 7
// 7625.672 us; speedup vs baseline: 1.4470x; 1.4380x over previous
//
#include <hip/hip_runtime.h>
#include <hip/hip_bf16.h>

typedef __attribute__((ext_vector_type(8))) _Float16 f16x8;
typedef __attribute__((ext_vector_type(4))) float floatx4;

#define T_SEQ 512
#define B_SZ  64
#define I_SZ  512
#define H_SZ  1024
#define NC    3072
#define NGRP  4            // independent batch groups (16 batches each)
#define WPG   64           // WGs per group (16 columns each)
#define MF(a,b,c) __builtin_amdgcn_mfma_f32_16x16x32_f16((a),(b),(c),0,0,0)

// ---------------- workspace layout (bytes) ----------------
// xproj fp16 [B*T][3072]                    : 201,326,592  (round-5 proven layout)
// exc: per group { h16[16][1024] | rh16[16][1024] } : 4 * 65,536
// flags u32 [4][64]                         : 1,024
static const size_t XPROJ_BYTES = (size_t)B_SZ * T_SEQ * NC * 2;
static const size_t EXC_OFF = XPROJ_BYTES;
static const size_t FLG_OFF = EXC_OFF + (size_t)NGRP * 65536;

__device__ __forceinline__ f16x8 cvt8(float4 a, float4 b) {
  f16x8 v;
  v[0] = (_Float16)a.x; v[1] = (_Float16)a.y; v[2] = (_Float16)a.z; v[3] = (_Float16)a.w;
  v[4] = (_Float16)b.x; v[5] = (_Float16)b.y; v[6] = (_Float16)b.z; v[7] = (_Float16)b.w;
  return v;
}

// ---------------- init: per-group h16 + flags ----------------
__global__ void init_kernel(const float* __restrict__ h0,
                            _Float16* __restrict__ exc,
                            unsigned* __restrict__ flags) {
  int i = blockIdx.x * blockDim.x + threadIdx.x;
  if (i < B_SZ * H_SZ) {
    int b = i >> 10, col = i & 1023;
    int grp = b >> 4, bl = b & 15;
    exc[(size_t)grp * 32768 + bl * 1024 + col] = (_Float16)h0[i];
  }
  if (i < NGRP * WPG) flags[i] = 0u;
}

// ---------------- pre-GEMM: xproj = x @ Wx^T + bias (fp16, round-5 proven) ----------------
__global__ __launch_bounds__(256) void pregemm_kernel(
    const float* __restrict__ X, const float* __restrict__ Wrz,
    const float* __restrict__ Wh, const float* __restrict__ brz,
    const float* __restrict__ bh, _Float16* __restrict__ xproj) {
  __shared__ __align__(16) char smem[128 * 64 * 2];
  char* Asb = smem;
  char* Bsb = smem + 128 * 64;
  const int tid = threadIdx.x;
  const int w = tid >> 6, l = tid & 63;
  const int lg = l >> 4, ln = l & 15;
  const int wm = w >> 1, wn = w & 1;
  const int m0 = blockIdx.x * 128;
  const int n0 = blockIdx.y * 128;
  const int rs = tid >> 1;
  const int ks = (tid & 1) * 16;

  floatx4 acc[4][4];
#pragma unroll
  for (int i = 0; i < 4; i++)
#pragma unroll
    for (int j = 0; j < 4; j++) acc[i][j] = (floatx4){0.f, 0.f, 0.f, 0.f};

  const float* garow = X + (size_t)(m0 + rs) * I_SZ + ks;
  const int nrow = n0 + rs;
  const float* gbrow = (nrow < 2048) ? (Wrz + (size_t)nrow * 1536 + ks)
                                     : (Wh + (size_t)(nrow - 2048) * 1536 + ks);
  for (int kt = 0; kt < I_SZ; kt += 32) {
    float4 a0 = ((const float4*)(garow + kt))[0];
    float4 a1 = ((const float4*)(garow + kt))[1];
    float4 a2 = ((const float4*)(garow + kt))[2];
    float4 a3 = ((const float4*)(garow + kt))[3];
    float4 b0 = ((const float4*)(gbrow + kt))[0];
    float4 b1 = ((const float4*)(gbrow + kt))[1];
    float4 b2 = ((const float4*)(gbrow + kt))[2];
    float4 b3 = ((const float4*)(gbrow + kt))[3];
    __syncthreads();
    {
      int c0 = ks >> 3;
      f16x8* wp = (f16x8*)(Asb + rs * 64);
      wp[(c0)     ^ (rs & 3)] = cvt8(a0, a1);
      wp[(c0 + 1) ^ (rs & 3)] = cvt8(a2, a3);
      f16x8* wq = (f16x8*)(Bsb + rs * 64);
      wq[(c0)     ^ (rs & 3)] = cvt8(b0, b1);
      wq[(c0 + 1) ^ (rs & 3)] = cvt8(b2, b3);
    }
    __syncthreads();
    f16x8 af[4], bf[4];
#pragma unroll
    for (int i = 0; i < 4; i++) {
      int ra = wm * 64 + i * 16 + ln;
      af[i] = ((const f16x8*)(Asb + ra * 64))[lg ^ (ra & 3)];
      int rb = wn * 64 + i * 16 + ln;
      bf[i] = ((const f16x8*)(Bsb + rb * 64))[lg ^ (rb & 3)];
    }
#pragma unroll
    for (int i = 0; i < 4; i++)
#pragma unroll
      for (int j = 0; j < 4; j++)
        acc[i][j] = MF(af[i], bf[j], acc[i][j]);
  }
#pragma unroll
  for (int j = 0; j < 4; j++) {
    int n = n0 + wn * 64 + j * 16 + ln;
    float bias = (n < 2048) ? (brz[n] + ((n >= 1024) ? 1.0f : 0.0f)) : bh[n - 2048];
#pragma unroll
    for (int i = 0; i < 4; i++) {
      int mrow = m0 + wm * 64 + i * 16 + 4 * lg;
#pragma unroll
      for (int q = 0; q < 4; q++) {
        xproj[(size_t)(mrow + q) * NC + n] = (_Float16)(acc[i][j][q] + bias);
      }
    }
  }
}

// ---------------- batched 8 x 16B device-coherent loads (one wait) ----------------
#define ALD8(X, P) do { asm volatile( \
  "global_load_dwordx4 %0, %8, off sc0 sc1\n\t" \
  "global_load_dwordx4 %1, %8, off offset:64 sc0 sc1\n\t" \
  "global_load_dwordx4 %2, %8, off offset:128 sc0 sc1\n\t" \
  "global_load_dwordx4 %3, %8, off offset:192 sc0 sc1\n\t" \
  "global_load_dwordx4 %4, %8, off offset:256 sc0 sc1\n\t" \
  "global_load_dwordx4 %5, %8, off offset:320 sc0 sc1\n\t" \
  "global_load_dwordx4 %6, %8, off offset:384 sc0 sc1\n\t" \
  "global_load_dwordx4 %7, %8, off offset:448 sc0 sc1\n\t" \
  "s_waitcnt vmcnt(0)" \
  : "=&v"(X[0]), "=&v"(X[1]), "=&v"(X[2]), "=&v"(X[3]), \
    "=&v"(X[4]), "=&v"(X[5]), "=&v"(X[6]), "=&v"(X[7]) \
  : "v"(P) : "memory"); \
  __builtin_amdgcn_sched_barrier(0); } while (0)

// Pack (even,odd) column pair across lane pair via shfl, one u32 agent store (proven).
__device__ __forceinline__ void pack_store_pair(unsigned* dst, int lane, int q,
                                                float v, size_t word) {
  _Float16 hh = (_Float16)v;
  unsigned short ms = __builtin_bit_cast(unsigned short, hh);
  unsigned ov = ((unsigned)__shfl_xor((int)ms, 1, 64)) & 0xffffu;
  unsigned wd = (lane & 1) ? (ov | ((unsigned)ms << 16)) : (((unsigned)ms) | (ov << 16));
  bool st = (q & 2) ? (bool)(lane & 1) : !(lane & 1);
  if (st)
    __hip_atomic_store(dst + word, wd, __ATOMIC_RELAXED, __HIP_MEMORY_SCOPE_AGENT);
}

// ---------------- persistent GRU: 4 groups x 64 WGs x 256 thr, K split over waves ----------------
__global__ __launch_bounds__(256) void gru_persistent_kernel(
    const float* __restrict__ Wrz, const float* __restrict__ Wh,
    const float* __restrict__ h0, const _Float16* __restrict__ xproj,
    float* __restrict__ Y, char* __restrict__ exc,
    unsigned* __restrict__ flags) {
  __shared__ __align__(16) char smem[48 * 2048 + 8192];  // weights | redR(4K) redZ(4K)
  floatx4* redR = (floatx4*)(smem + 98304);
  floatx4* redZ = redR + 256;

  const int bid = blockIdx.x;
  const int grp = bid >> 6;          // batch group 0..3
  const int c   = bid & 63;          // column block 0..63
  const int tid = threadIdx.x;
  const int w = tid >> 6, l = tid & 63;
  const int lg = l >> 4, ln = l & 15;
  const int sw = ln & 7;
  const int colbase = 16 * c;
  const int jg = colbase + ln;
  const int b0 = 16 * grp;

  // weights -> LDS: rows 0-15 r, 16-31 z, 32-47 h; k = 512..1535, XOR-swizzled (proven)
  for (int it = tid; it < 48 * 128; it += 256) {
    int r = it >> 7, cc = it & 127;
    const float* src;
    if (r < 16)      src = Wrz + (size_t)(colbase + r) * 1536 + 512 + cc * 8;
    else if (r < 32) src = Wrz + (size_t)(1024 + colbase + (r - 16)) * 1536 + 512 + cc * 8;
    else             src = Wh  + (size_t)(colbase + (r - 32)) * 1536 + 512 + cc * 8;
    float4 f0 = ((const float4*)src)[0];
    float4 f1 = ((const float4*)src)[1];
    ((f16x8*)(smem + (size_t)r * 2048))[cc ^ (r & 7)] = cvt8(f0, f1);
  }
  __syncthreads();

  const f16x8* bpr = (const f16x8*)(smem + (size_t)ln * 2048);
  const f16x8* bpz = (const f16x8*)(smem + (size_t)(16 + ln) * 2048);
  const f16x8* bph = (const f16x8*)(smem + (size_t)(32 + ln) * 2048);

  _Float16* h16g  = (_Float16*)(exc + (size_t)grp * 65536);
  _Float16* rh16g = h16g + 16384;
  unsigned* h16w  = (unsigned*)h16g;
  unsigned* rh16w = (unsigned*)rh16g;
  unsigned* flg   = flags + grp * WPG;

  // wave w covers K halves [256w, 256w+256): fragment i at +32*(8w+i) halves
  const _Float16* apA = h16g  + (size_t)ln * 1024 + 256 * w + 8 * lg;
  const _Float16* apB = rh16g + (size_t)ln * 1024 + 256 * w + 8 * lg;

  // wave-0-only state: fp32 master h, gate z, staged x-projections
  float hm[4], zq[4], xr[4], xz[4], xh[4];
#define XPRE(T) { \
  _Pragma("unroll") for (int q_ = 0; q_ < 4; ++q_) { \
    size_t row_ = ((size_t)(b0 + 4 * lg + q_) * T_SEQ + (T)) * NC; \
    xr[q_] = (float)xproj[row_ + jg]; \
    xz[q_] = (float)xproj[row_ + 1024 + jg]; \
    xh[q_] = (float)xproj[row_ + 2048 + jg]; } }
  if (w == 0) {
#pragma unroll
    for (int q = 0; q < 4; ++q)
      hm[q] = h0[(size_t)(b0 + 4 * lg + q) * H_SZ + jg];
    XPRE(0)
  }

  unsigned bar = 0;
  for (int t = 0; t < T_SEQ; ++t) {
    // ---------------- phase A: r,z (all waves: K-quarter partials) ----------------
    {
      f16x8 Af[8];
      ALD8(Af, apA);
      floatx4 ar = {0.f,0.f,0.f,0.f}, az = {0.f,0.f,0.f,0.f};
#pragma unroll
      for (int i = 0; i < 8; ++i) {
        int ki = 8 * w + i;
        ar = MF(Af[i], bpr[(4 * ki + lg) ^ sw], ar);
        az = MF(Af[i], bpz[(4 * ki + lg) ^ sw], az);
      }
      redR[tid] = ar;
      redZ[tid] = az;
    }
    __syncthreads();
    ++bar;
    if (w == 0) {
      floatx4 Dr = redR[l] + redR[64 + l] + redR[128 + l] + redR[192 + l];
      floatx4 Dz = redZ[l] + redZ[64 + l] + redZ[128 + l] + redZ[192 + l];
#pragma unroll
      for (int q = 0; q < 4; ++q) {
        float rr = 1.f / (1.f + __expf(-(Dr[q] + xr[q])));
        zq[q]    = 1.f / (1.f + __expf(-(Dz[q] + xz[q])));
        pack_store_pair(rh16w, l, q, rr * hm[q],
                        (size_t)(4 * lg + q) * 512 + (jg >> 1));
      }
      asm volatile("s_waitcnt vmcnt(0)" ::: "memory");
      if (tid == 0)
        __hip_atomic_store(&flg[c], bar, __ATOMIC_RELAXED, __HIP_MEMORY_SCOPE_AGENT);
    }
    {
      unsigned v;
      do { v = __hip_atomic_load(&flg[l], __ATOMIC_RELAXED, __HIP_MEMORY_SCOPE_AGENT); }
      while (__all((int)(v >= bar)) == 0);
    }
    // ---------------- phase B: hhat, h' ----------------
    {
      f16x8 Bf[8];
      ALD8(Bf, apB);
      floatx4 ah = {0.f,0.f,0.f,0.f};
#pragma unroll
      for (int i = 0; i < 8; ++i) {
        int ki = 8 * w + i;
        ah = MF(Bf[i], bph[(4 * ki + lg) ^ sw], ah);
      }
      redR[tid] = ah;
    }
    __syncthreads();
    ++bar;
    if (w == 0) {
      floatx4 Dh = redR[l] + redR[64 + l] + redR[128 + l] + redR[192 + l];
      float hnv[4];
#pragma unroll
      for (int q = 0; q < 4; ++q) {
        float hh = tanhf(Dh[q] + xh[q]);
        float hn = zq[q] * hm[q] + (1.f - zq[q]) * hh;
        hm[q] = hn; hnv[q] = hn;
        pack_store_pair(h16w, l, q, hn,
                        (size_t)(4 * lg + q) * 512 + (jg >> 1));
      }
      asm volatile("s_waitcnt vmcnt(0)" ::: "memory");
      if (tid == 0)
        __hip_atomic_store(&flg[c], bar, __ATOMIC_RELAXED, __HIP_MEMORY_SCOPE_AGENT);
      // off critical path: Y stores + next-step xproj prefetch ride under the wait
#pragma unroll
      for (int q = 0; q < 4; ++q)
        Y[((size_t)(b0 + 4 * lg + q) * T_SEQ + t) * H_SZ + jg] = hnv[q];
      if (t + 1 < T_SEQ) XPRE(t + 1)
    }
    {
      unsigned v;
      do { v = __hip_atomic_load(&flg[l], __ATOMIC_RELAXED, __HIP_MEMORY_SCOPE_AGENT); }
      while (__all((int)(v >= bar)) == 0);
    }
  }
}

// ---------------- launch ----------------
extern "C" void kernel_launch(void* const* d_in, const int* in_sizes, int n_in,
                              void* d_out, int out_size, void* d_ws, size_t ws_size,
                              hipStream_t stream) {
  const float* X   = (const float*)d_in[0];
  const float* h0  = (const float*)d_in[1];
  const float* Wrz = (const float*)d_in[2];
  const float* brz = (const float*)d_in[3];
  const float* Wh  = (const float*)d_in[4];
  const float* bh  = (const float*)d_in[5];
  float* Y = (float*)d_out;
  char* ws = (char*)d_ws;

  _Float16* xproj = (_Float16*)(ws);
  char*     exc   = ws + EXC_OFF;
  unsigned* flags = (unsigned*)(ws + FLG_OFF);

  hipLaunchKernelGGL(init_kernel, dim3(256), dim3(256), 0, stream,
                     h0, (_Float16*)exc, flags);
  hipLaunchKernelGGL(pregemm_kernel, dim3(256, 24), dim3(256), 0, stream,
                     X, Wrz, Wh, brz, bh, xproj);

  void* kargs[] = { (void*)&Wrz, (void*)&Wh, (void*)&h0, (void*)&xproj,
                    (void*)&Y, (void*)&exc, (void*)&flags };
  hipError_t ce = hipLaunchCooperativeKernel((void*)gru_persistent_kernel,
                                             dim3(NGRP * WPG), dim3(256), kargs, 0, stream);
  if (ce != hipSuccess) {
    // 256 WGs x ~104KB LDS = 1/CU on 256 CUs: co-resident under plain launch too
    hipLaunchKernelGGL(gru_persistent_kernel, dim3(NGRP * WPG), dim3(256), 0, stream,
                       Wrz, Wh, h0, xproj, Y, exc, flags);
  }
}